// Round 6
// baseline (517.534 us; speedup 1.0000x reference)
//
#include <hip/hip_runtime.h>
#include <hip/hip_bf16.h>
#include <type_traits>

// B=8, S=1024, H=512, NH=8, DH=64, FFN=2048. Inputs fp32, output fp32 (verified R0-R6).
// ws_size >= 32 MiB (proven R6/R7).
static constexpr int kS   = 1024;
static constexpr int kH   = 512;
static constexpr int kFFN = 2048;

using bf16 = __hip_bfloat16;
using short8  = __attribute__((ext_vector_type(8))) short;
using float4v = __attribute__((ext_vector_type(4))) float;
#define MFMA16 __builtin_amdgcn_mfma_f32_16x16x32_bf16

__device__ __forceinline__ unsigned short f2bfu(float f){
  unsigned int u = __float_as_uint(f);
  return (unsigned short)((u + 0x7fffu + ((u >> 16) & 1u)) >> 16);   // RNE
}
__device__ __forceinline__ float bfu2f(unsigned short u){
  return __uint_as_float(((unsigned int)u) << 16);
}
// manual RNE pack (proven R0-R3; the v_cvt_pk_bf16_f32 asm variant broke R4)
__device__ __forceinline__ unsigned int pack2(float a, float b){
  return (unsigned int)f2bfu(a) | ((unsigned int)f2bfu(b) << 16);
}
// async 16B global->LDS (per-lane gptr; LDS dest = base + lane*16)
__device__ __forceinline__ void async16(const void* g, void* l){
  __builtin_amdgcn_global_load_lds(
    (const __attribute__((address_space(1))) unsigned int*)g,
    (__attribute__((address_space(3))) unsigned int*)l, 16, 0, 0);
}
// swizzle: permute 8-elem k-groups within each 64-elem block by row&7
__device__ __forceinline__ int swz(int col, int row){
  return (col & ~63) | (((((col>>3)&7) ^ (row&7)))<<3) | (col&7);
}

// ---------- LayerNorm row body: one wave per row (fp32 in, swizzled bf16 out) ----------
__device__ __forceinline__ void ln_row(const float* __restrict__ x,
    const float* __restrict__ g, const float* __restrict__ bb,
    bf16* __restrict__ y, long row, int lane){
  const float* xr = x + row * kH + lane*8;
  float4 a = *(const float4*)xr, c = *(const float4*)(xr+4);
  float v[8] = {a.x,a.y,a.z,a.w,c.x,c.y,c.z,c.w};
  float s=0.f, s2=0.f;
#pragma unroll
  for(int i=0;i<8;i++){ s += v[i]; s2 += v[i]*v[i]; }
#pragma unroll
  for(int o=32; o>=1; o>>=1){ s += __shfl_xor(s,o,64); s2 += __shfl_xor(s2,o,64); }
  float mu  = s * (1.f/kH);
  float rs  = rsqrtf(s2*(1.f/kH) - mu*mu + 1e-5f);
  float gv[8], bv[8];
  {
    float4 t0=*(const float4*)(g+lane*8),  t1=*(const float4*)(g+lane*8+4);
    float4 t2=*(const float4*)(bb+lane*8), t3=*(const float4*)(bb+lane*8+4);
    gv[0]=t0.x;gv[1]=t0.y;gv[2]=t0.z;gv[3]=t0.w;gv[4]=t1.x;gv[5]=t1.y;gv[6]=t1.z;gv[7]=t1.w;
    bv[0]=t2.x;bv[1]=t2.y;bv[2]=t2.z;bv[3]=t2.w;bv[4]=t3.x;bv[5]=t3.y;bv[6]=t3.z;bv[7]=t3.w;
  }
  unsigned int ow[4];
#pragma unroll
  for(int i=0;i<4;i++){
    float a0 = (v[2*i]  -mu)*rs*gv[2*i]   + bv[2*i];
    float a1 = (v[2*i+1]-mu)*rs*gv[2*i+1] + bv[2*i+1];
    ow[i] = pack2(a0, a1);
  }
  *reinterpret_cast<uint4*>(y + row*kH + swz(lane*8, (int)row)) = make_uint4(ow[0],ow[1],ow[2],ow[3]);
}

__global__ __launch_bounds__(256) void ln_kernel(const float* __restrict__ x,
    const float* __restrict__ g, const float* __restrict__ bb, bf16* __restrict__ y){
  ln_row(x, g, bb, y, (long)blockIdx.x*4 + (threadIdx.x>>6), threadIdx.x&63);
}

// ---------- weight prep tile body: W[K,N] fp32 -> WT[N,K] bf16, k-group swizzled ----------
__device__ __forceinline__ void prep_tile(const float* __restrict__ W,
    bf16* __restrict__ WT, int K, int N, int kb, int nb){
  __shared__ unsigned short Ts[64*68];
  int tid=threadIdx.x;
  {
    int k=tid>>2, nc=(tid&3)*16;
    const float* p = W + (size_t)(kb+k)*N + nb+nc;
#pragma unroll
    for(int i=0;i<16;i+=4){
      float4 f = *(const float4*)(p+i);
      Ts[k*68+nc+i  ]=f2bfu(f.x); Ts[k*68+nc+i+1]=f2bfu(f.y);
      Ts[k*68+nc+i+2]=f2bfu(f.z); Ts[k*68+nc+i+3]=f2bfu(f.w);
    }
  }
  __syncthreads();
  {
    int n=tid>>2, kc=(tid&3)*16;
    unsigned short tmp[16];
#pragma unroll
    for(int i=0;i<16;i++) tmp[i] = Ts[(kc+i)*68 + n];
    int row = nb+n, kg0 = kc>>3;
    bf16* op = WT + (size_t)row*K + kb;
    *(uint4*)(op + (((kg0  ^(row&7)))<<3)) = *(uint4*)&tmp[0];
    *(uint4*)(op + ((((kg0+1)^(row&7)))<<3)) = *(uint4*)&tmp[8];
  }
}

// ---------- merged: ln1 (0..2047) + ALL weight preps (2048..2815) ----------
// pid<64:Wq  <128:Wk  <192:Wv  <256:Wo  <512:W1  <768:W2
__global__ __launch_bounds__(256) void ln1_prep_all(
    const float* __restrict__ x, const float* __restrict__ g, const float* __restrict__ bb,
    bf16* __restrict__ y, const float* __restrict__ Wq, const float* __restrict__ Wk,
    const float* __restrict__ Wv, bf16* __restrict__ WqkvT,
    const float* __restrict__ Wo, const float* __restrict__ W1, const float* __restrict__ W2,
    bf16* __restrict__ WoT, bf16* __restrict__ W1T, bf16* __restrict__ W2T){
  int id = blockIdx.x;
  if(id < 2048){
    ln_row(x, g, bb, y, (long)id*4 + (threadIdx.x>>6), threadIdx.x&63);
    return;
  }
  int pid = id - 2048;
  const float* W; bf16* WT; int K, N, kb, nb;
  if(pid < 192){
    int sel = pid>>6, lid = pid&63;
    W = sel==0 ? Wq : (sel==1 ? Wk : Wv);
    WT = WqkvT + (size_t)sel*262144;
    K=kH; N=kH; kb=(lid>>3)*64; nb=(lid&7)*64;
  } else if(pid < 256){
    int l=pid-192; W=Wo; WT=WoT; K=kH; N=kH; kb=(l>>3)*64; nb=(l&7)*64;
  } else if(pid < 512){
    int l=pid-256; W=W1; WT=W1T; K=kH; N=kFFN; kb=(l>>5)*64; nb=(l&31)*64;
  } else {
    int l=pid-512; W=W2; WT=W2T; K=kFFN; N=kH; kb=(l>>3)*64; nb=(l&7)*64;
  }
  prep_tile(W, WT, K, N, kb, nb);
}

// ---------- m97-style MFMA GEMM, generalized tile (BM x BN), 64x64 per wave ----------
template<int BM, int BN, typename OutT, bool SCALE, bool GELU, bool RES, bool CSW>
__global__ __launch_bounds__((BM/64)*(BN/64)*64, 3) void mfma_gemm(
    const bf16* __restrict__ A, const bf16* __restrict__ BT,
    const float* __restrict__ bias, const float* __restrict__ res,
    OutT* __restrict__ C, int M, int N, int K)
{
  constexpr int W  = (BM/64)*(BN/64);
  constexpr int NW = BN/64;
  constexpr int AC = (BM/8)/W, BC = (BN/8)/W;
  __shared__ __align__(16) unsigned short As[BM*64];
  __shared__ __align__(16) unsigned short Bs[BN*64];
  int tid=threadIdx.x, lane=tid&63, quad=lane>>4, l16=lane&15;
  int w=__builtin_amdgcn_readfirstlane(tid>>6);
  int wr = w / NW, wc = w % NW;
  int m0=blockIdx.y*BM, n0=blockIdx.x*BN;
  int lr=lane>>3, lc=lane&7;
  float4v acc[4][4] = {};
  for(int k0=0;k0<K;k0+=64){
    __syncthreads();
#pragma unroll
    for(int i=0;i<AC;i++){
      int r = (w*AC+i)*8;
      async16(A + (size_t)(m0+r+lr)*K + k0 + lc*8, &As[r*64]);
    }
#pragma unroll
    for(int i=0;i<BC;i++){
      int r = (w*BC+i)*8;
      async16(BT + (size_t)(n0+r+lr)*K + k0 + lc*8, &Bs[r*64]);
    }
    __syncthreads();
#pragma unroll
    for(int hf=0;hf<2;hf++){
      short8 af[4], bfv[4];
#pragma unroll
      for(int mi=0;mi<4;mi++){
        int row=wr*64+mi*16+l16;
        af[mi]=*(const short8*)&As[row*64 + (((hf*4+quad)^(row&7))<<3)];
      }
#pragma unroll
      for(int ni=0;ni<4;ni++){
        int n=wc*64+ni*16+l16;
        bfv[ni]=*(const short8*)&Bs[n*64 + (((hf*4+quad)^(n&7))<<3)];
      }
#pragma unroll
      for(int ni=0;ni<4;ni++)
#pragma unroll
        for(int mi=0;mi<4;mi++)
          acc[mi][ni]=MFMA16(af[mi],bfv[ni],acc[mi][ni],0,0,0);
    }
  }
#pragma unroll
  for(int ni=0;ni<4;ni++){
    int col=n0+wc*64+ni*16+l16;
    float bc=bias[col];
#pragma unroll
    for(int mi=0;mi<4;mi++){
#pragma unroll
      for(int r=0;r<4;r++){
        int row=m0+wr*64+mi*16+quad*4+r;
        float v=acc[mi][ni][r]+bc;
        if constexpr(SCALE) v*=0.125f;
        if constexpr(GELU)  v=0.5f*v*(1.f+erff(v*0.70710678118f));
        size_t idx=(size_t)row*N+col;
        if constexpr(RES) v+=res[idx];
        if constexpr(std::is_same<OutT,float>::value) C[idx]=v;
        else {
          size_t ix = CSW ? ((size_t)row*N + swz(col,row)) : idx;
          reinterpret_cast<unsigned short*>(C)[ix]=f2bfu(v);
        }
      }
    }
  }
}

// ---------- quad GEMM: 64x64 tile, 4 waves (each a 32x32 quadrant), fp32 out + residual ----
__global__ __launch_bounds__(256, 4) void quad_gemm(
    const bf16* __restrict__ A, const bf16* __restrict__ BT,
    const float* __restrict__ bias, const float* __restrict__ res,
    float* __restrict__ C, int M, int N, int K)
{
  __shared__ __align__(16) unsigned short As[64*64];
  __shared__ __align__(16) unsigned short Bs[64*64];
  int tid=threadIdx.x, lane=tid&63, quad=lane>>4, l16=lane&15;
  int w=__builtin_amdgcn_readfirstlane(tid>>6);
  int wr=w>>1, wc=w&1;
  int m0=blockIdx.y*64, n0=blockIdx.x*64;
  int lr=lane>>3, lc=lane&7;
  float4v acc[2][2]={};
  for(int k0=0;k0<K;k0+=64){
    __syncthreads();
#pragma unroll
    for(int i=0;i<2;i++){
      int r=(w*2+i)*8;
      async16(A  + (size_t)(m0+r+lr)*K + k0 + lc*8, &As[r*64]);
      async16(BT + (size_t)(n0+r+lr)*K + k0 + lc*8, &Bs[r*64]);
    }
    __syncthreads();
#pragma unroll
    for(int hf=0;hf<2;hf++){
      short8 af[2], bfv[2];
#pragma unroll
      for(int mi=0;mi<2;mi++){
        int row=wr*32+mi*16+l16;
        af[mi]=*(const short8*)&As[row*64 + (((hf*4+quad)^(row&7))<<3)];
      }
#pragma unroll
      for(int ni=0;ni<2;ni++){
        int n=wc*32+ni*16+l16;
        bfv[ni]=*(const short8*)&Bs[n*64 + (((hf*4+quad)^(n&7))<<3)];
      }
#pragma unroll
      for(int ni=0;ni<2;ni++)
#pragma unroll
        for(int mi=0;mi<2;mi++)
          acc[mi][ni]=MFMA16(af[mi],bfv[ni],acc[mi][ni],0,0,0);
    }
  }
#pragma unroll
  for(int ni=0;ni<2;ni++){
    int col=n0+wc*32+ni*16+l16;
    float bc=bias[col];
#pragma unroll
    for(int mi=0;mi<2;mi++){
#pragma unroll
      for(int r=0;r<4;r++){
        int row=m0+wr*32+mi*16+quad*4+r;
        float v=acc[mi][ni][r]+bc;
        size_t idx=(size_t)row*N+col;
        v+=res[idx];
        C[idx]=v;
      }
    }
  }
}

// ---------- fused QKV GEMM: 128x128 tile; BT = [Wq|Wk|Wv]^T rows 0..1535 ----------
__global__ __launch_bounds__(256, 3) void mfma_gemm_qkv(
    const bf16* __restrict__ A, const bf16* __restrict__ BT,
    const float* __restrict__ bq, const float* __restrict__ bk, const float* __restrict__ bv,
    bf16* __restrict__ qo, bf16* __restrict__ ko, bf16* __restrict__ vT, int M, int N, int K)
{
  __shared__ __align__(16) unsigned short As[128*64];
  __shared__ __align__(16) unsigned short Bs[128*64];
  int tid=threadIdx.x, lane=tid&63, quad=lane>>4, l16=lane&15;
  int w=__builtin_amdgcn_readfirstlane(tid>>6);
  int wr = w >> 1, wc = w & 1;
  int m0=blockIdx.y*128, n0=blockIdx.x*128;
  int lr=lane>>3, lc=lane&7;
  float4v acc[4][4] = {};
  for(int k0=0;k0<K;k0+=64){
    __syncthreads();
#pragma unroll
    for(int i=0;i<4;i++){
      int r = (w*4+i)*8;
      async16(A + (size_t)(m0+r+lr)*K + k0 + lc*8, &As[r*64]);
    }
#pragma unroll
    for(int i=0;i<4;i++){
      int r = (w*4+i)*8;
      async16(BT + (size_t)(n0+r+lr)*K + k0 + lc*8, &Bs[r*64]);
    }
    __syncthreads();
#pragma unroll
    for(int hf=0;hf<2;hf++){
      short8 af[4], bfv[4];
#pragma unroll
      for(int mi=0;mi<4;mi++){
        int row=wr*64+mi*16+l16;
        af[mi]=*(const short8*)&As[row*64 + (((hf*4+quad)^(row&7))<<3)];
      }
#pragma unroll
      for(int ni=0;ni<4;ni++){
        int n=wc*64+ni*16+l16;
        bfv[ni]=*(const short8*)&Bs[n*64 + (((hf*4+quad)^(n&7))<<3)];
      }
#pragma unroll
      for(int ni=0;ni<4;ni++)
#pragma unroll
        for(int mi=0;mi<4;mi++)
          acc[mi][ni]=MFMA16(af[mi],bfv[ni],acc[mi][ni],0,0,0);
    }
  }
  int sec = __builtin_amdgcn_readfirstlane(n0 >> 9);    // 0=q, 1=k, 2=v (block-uniform)
  const float* bp = sec==0 ? bq : (sec==1 ? bk : bv);
  if(sec == 2){
#pragma unroll
    for(int ni=0;ni<4;ni++){
      int cl=(n0+wc*64+ni*16+l16)&511;
      float bc=bp[cl];
#pragma unroll
      for(int mi=0;mi<4;mi++){
        int row0=m0+wr*64+mi*16+quad*4;
        unsigned int p0=pack2(acc[mi][ni][0]+bc, acc[mi][ni][1]+bc);
        unsigned int p1=pack2(acc[mi][ni][2]+bc, acc[mi][ni][3]+bc);
        *reinterpret_cast<uint2*>(reinterpret_cast<unsigned short*>(vT)
            + (size_t)cl*8192 + row0) = make_uint2(p0,p1);
      }
    }
  } else {
    unsigned short* dst = (unsigned short*)(sec==0 ? qo : ko);
    float scl = (sec==0) ? 0.125f : 1.0f;
#pragma unroll
    for(int ni=0;ni<4;ni++){
      int col=n0+wc*64+ni*16+l16, cl=col&511;
      float bc=bp[cl];
#pragma unroll
      for(int mi=0;mi<4;mi++){
#pragma unroll
        for(int r=0;r<4;r++){
          int row=m0+wr*64+mi*16+quad*4+r;
          dst[(size_t)row*512+cl]=f2bfu((acc[mi][ni][r]+bc)*scl);
        }
      }
    }
  }
}

// ---------- MFMA flash attention (fixed-max softmax, 2-phase, 128 q-rows/block) ----------
// Grid 512 = 8 q-tiles x 64 bh, XCD-swizzled (each XCD owns one batch b).
// 4 waves; wave w owns q-rows w*32..+31 as two 16-row groups g=0,1 (independent chains).
// S C-init computed inline from graph_mask/attn_bias (fp32): bev = m ? bias : -1e9.
__global__ __launch_bounds__(256,2) void attn_mfma(
    const bf16* __restrict__ q, const bf16* __restrict__ k,
    const bf16* __restrict__ vT, const int* __restrict__ gmask,
    const float* __restrict__ abias, bf16* __restrict__ o)
{
  __shared__ __align__(16) unsigned short Ks[2][64*64];   // [key][d] xor-swizzled
  __shared__ __align__(16) unsigned short Vt[2][64*64];   // [d][key] xor-swizzled
  __shared__ __align__(16) unsigned short Ps[4*32*72];    // per-wave P (32 rows), stride 72
  int tid=threadIdx.x, lane=tid&63, quad=lane>>4, l16=lane&15;
  int w=__builtin_amdgcn_readfirstlane(tid>>6);
  // XCD swizzle: 512 blocks = 8 XCDs x 64; XCD x gets bh 8x..8x+7 (= batch x, all heads)
  int lin = blockIdx.x;
  int nid = (lin&7)*64 + (lin>>3);
  int q0=(nid&7)*128, bh=nid>>3, b=bh>>3, h=bh&7;
  int lr=lane>>3, lc=lane&7;
  short8 aq[2][2];
#pragma unroll
  for(int g=0;g<2;g++){
    const bf16* qp = q + (size_t)(b*kS + q0 + w*32 + g*16 + l16)*kH + h*64;
    aq[g][0] = *(const short8*)(qp + quad*8);
    aq[g][1] = *(const short8*)(qp + 32 + quad*8);
  }
  float lpart[2][4]={};
  float4v oacc[2][4]={};
  int pb = w*32*72;
  const float* biasRow[2][4];
  const int*   maskRow[2][4];
#pragma unroll
  for(int g=0;g<2;g++)
#pragma unroll
    for(int r=0;r<4;r++){
      size_t off = (size_t)(b*kS+q0+w*32+g*16+quad*4+r)*kS + l16;
      biasRow[g][r] = abias + off;
      maskRow[g][r] = gmask + off;
    }

  auto stage = [&](int kt, int bufi){
    int kb = kt*64;
#pragma unroll
    for(int i=0;i<2;i++){
      int rr = w*16 + i*8;
      async16(k  + (size_t)(b*kS+kb+rr+lr)*kH + h*64 + ((lc^lr)<<3), &Ks[bufi][rr*64]);
      async16(vT + (size_t)(h*64+rr+lr)*8192 + b*kS + kb + ((lc^lr)<<3), &Vt[bufi][rr*64]);
    }
  };
  float bevc[2][4][4];   // [g][r][t] C-init for current tile (prefetched)
  stage(0,0);
#pragma unroll
  for(int g=0;g<2;g++)
#pragma unroll
    for(int r=0;r<4;r++)
#pragma unroll
      for(int t=0;t<4;t++)
        bevc[g][r][t] = maskRow[g][r][t*16] ? biasRow[g][r][t*16] : -1e9f;
  __syncthreads();
  for(int kt=0;kt<16;kt++){
    int cur=kt&1;
    if(kt<15) stage(kt+1, cur^1);          // next tile's K/V loads in flight over compute
    // S = Q·K^T + bias (two independent 16-row chains)
    float4v sa[2][4];
#pragma unroll
    for(int t=0;t<4;t++){
      int krow=t*16+l16, kx=krow&7;
      short8 b0 = *(const short8*)&Ks[cur][krow*64 + ((quad^kx)<<3)];
      short8 b1 = *(const short8*)&Ks[cur][krow*64 + (((4+quad)^kx)<<3)];
#pragma unroll
      for(int g=0;g<2;g++){
        float4v ci;
#pragma unroll
        for(int r=0;r<4;r++) ci[r] = bevc[g][r][t];
        ci = MFMA16(aq[g][0],b0,ci,0,0,0);
        sa[g][t]=MFMA16(aq[g][1],b1,ci,0,0,0);
      }
    }
    // prefetch next tile's C-init (bevc dead after QK; latency hides under SM+PV)
    if(kt<15){
      int kb2=(kt+1)*64;
#pragma unroll
      for(int g=0;g<2;g++)
#pragma unroll
        for(int r=0;r<4;r++)
#pragma unroll
          for(int t=0;t<4;t++)
            bevc[g][r][t] = maskRow[g][r][kb2 + t*16] ? biasRow[g][r][kb2 + t*16] : -1e9f;
    }
    // fixed-max softmax: P = exp(s - 24); defer cross-lane l-reduction
#pragma unroll
    for(int g=0;g<2;g++)
#pragma unroll
    for(int t=0;t<4;t++){
      int kg = t*2 + (l16>>3), j = l16&7;
#pragma unroll
      for(int r=0;r<4;r++){
        float p = __expf(sa[g][t][r] - 24.f);
        lpart[g][r] += p;
        int row = g*16 + quad*4+r;
        Ps[pb + row*72 + ((kg^(row&7))<<3) + j] = f2bfu(p);
      }
    }
    short8 ap[2][2];
#pragma unroll
    for(int g=0;g<2;g++){
      int prow = g*16 + l16;
      ap[g][0] = *(const short8*)&Ps[pb + prow*72 + ((quad^(prow&7))<<3)];
      ap[g][1] = *(const short8*)&Ps[pb + prow*72 + (((4+quad)^(prow&7))<<3)];
    }
#pragma unroll
    for(int dt=0;dt<4;dt++){
      int vrow=dt*16+l16, vx=vrow&7;
      short8 bv0=*(const short8*)&Vt[cur][vrow*64+((quad^vx)<<3)];
      short8 bv1=*(const short8*)&Vt[cur][vrow*64+(((4+quad)^vx)<<3)];
#pragma unroll
      for(int g=0;g<2;g++){
        oacc[g][dt]=MFMA16(ap[g][0],bv0,oacc[g][dt],0,0,0);
        oacc[g][dt]=MFMA16(ap[g][1],bv1,oacc[g][dt],0,0,0);
      }
    }
    __syncthreads();   // next buffer staged + all waves done reading [cur]
  }
#pragma unroll
  for(int g=0;g<2;g++){
    float inv[4];
#pragma unroll
    for(int r=0;r<4;r++){
      float l = lpart[g][r];
      l += __shfl_xor(l,1,64); l += __shfl_xor(l,2,64);
      l += __shfl_xor(l,4,64); l += __shfl_xor(l,8,64);
      inv[r] = 1.f/l;
    }
#pragma unroll
    for(int dt=0;dt<4;dt++)
#pragma unroll
      for(int r=0;r<4;r++){
        int row = b*kS + q0 + w*32 + g*16 + quad*4 + r;
        int col = h*64 + dt*16 + l16;
        reinterpret_cast<unsigned short*>(o)[(size_t)row*kH + swz(col,row)] =
          f2bfu(oacc[g][dt][r]*inv[r]);
      }
  }
}

// ---------- launch ----------
extern "C" void kernel_launch(void* const* d_in, const int* in_sizes, int n_in,
                              void* d_out, int out_size, void* d_ws, size_t ws_size,
                              hipStream_t stream){
  (void)in_sizes; (void)n_in; (void)out_size; (void)ws_size;
  const float* x         = (const float*)d_in[0];
  const float* attn_bias = (const float*)d_in[1];
  const int*   graph_mask= (const int*)  d_in[2];
  const float* ln1_g = (const float*)d_in[3];
  const float* ln1_b = (const float*)d_in[4];
  const float* Wq = (const float*)d_in[5];
  const float* bq = (const float*)d_in[6];
  const float* Wk = (const float*)d_in[7];
  const float* bk = (const float*)d_in[8];
  const float* Wv = (const float*)d_in[9];
  const float* bv = (const float*)d_in[10];
  const float* Wo = (const float*)d_in[11];
  const float* bo = (const float*)d_in[12];
  const float* ln2_g = (const float*)d_in[13];
  const float* ln2_b = (const float*)d_in[14];
  const float* W1 = (const float*)d_in[15];
  const float* b1 = (const float*)d_in[16];
  const float* W2 = (const float*)d_in[17];
  const float* b2 = (const float*)d_in[18];

  // ws (32 MiB): s0 y1->O->y2 | s1 q->h | s2 k->h | s3 WoT/W1T/W2T (prepped early)
  // d_out (16 MiB): WqkvT[0..1.5M] + vT[8M..16M] during attn -> outf (final) after.
  char* wsb = (char*)d_ws;
  const size_t SZ = (size_t)8192 * kH * sizeof(bf16);   // 8 MiB
  bf16* s0 = (bf16*)(wsb);
  bf16* s1 = (bf16*)(wsb + SZ);
  bf16* s2 = (bf16*)(wsb + 2*SZ);
  bf16* s3 = (bf16*)(wsb + 3*SZ);
  float* outf = (float*)d_out;
  bf16*  WqkvT = (bf16*)d_out;                              // 1.5 MiB
  bf16*  vT    = (bf16*)((char*)d_out + (8u<<20));          // 8 MiB
  bf16* WoT = s3;
  bf16* W1T = s3 + 262144;
  bf16* W2T = s3 + 262144 + 1048576;

  dim3 blk(256);
  // 1: LN1 + ALL weight transposes (one dispatch)
  ln1_prep_all<<<dim3(2816), blk, 0, stream>>>(x, ln1_g, ln1_b, s0,
      Wq, Wk, Wv, WqkvT, Wo, W1, W2, WoT, W1T, W2T);
  // 2: fused QKV: q->s1 (scaled), k->s2, v->vT (d_out+8M, transposed)
  mfma_gemm_qkv<<<dim3(12,64), blk, 0, stream>>>(s0, WqkvT, bq, bk, bv, s1, s2, vT, 8192, 3*kH, kH);
  // 3: attention (bias/mask inlined; writes O -> s0)
  attn_mfma<<<dim3(512), blk, 0, stream>>>(s1, s2, vT, graph_mask, attn_bias, s0);
  // 4: O-proj + residual (overwrites d_out; WqkvT/vT dead)
  quad_gemm<<<dim3(8,128), blk, 0, stream>>>(s0, WoT, bo, x, outf, 8192, kH, kH);
  // 5: LN2
  ln_kernel<<<dim3(2048), blk, 0, stream>>>(outf, ln2_g, ln2_b, s0);
  // 6-9: FFN, 2 chunks of 4096 rows; h (16 MiB) spans s1+s2
  for(int c=0;c<2;c++){
    size_t ro = (size_t)c * 4096 * kH;
    mfma_gemm<128,128,bf16,false,true ,false,true ><<<dim3(16,32), blk, 0, stream>>>(s0 + ro, W1T, b1, nullptr, s1, 4096, kFFN, kH);
    quad_gemm<<<dim3(8,64), blk, 0, stream>>>(s1, W2T, b2, outf + ro, outf + ro, 4096, kH, kFFN);
  }
}

// Round 7
// 323.554 us; speedup vs baseline: 1.5995x; 1.5995x over previous
//
#include <hip/hip_runtime.h>
#include <hip/hip_bf16.h>
#include <type_traits>

// B=8, S=1024, H=512, NH=8, DH=64, FFN=2048. Inputs fp32, output fp32 (verified R0-R6).
// ws_size >= 32 MiB (proven R6/R7).
static constexpr int kS   = 1024;
static constexpr int kH   = 512;
static constexpr int kFFN = 2048;

using bf16 = __hip_bfloat16;
using short8  = __attribute__((ext_vector_type(8))) short;
using float4v = __attribute__((ext_vector_type(4))) float;
#define MFMA16 __builtin_amdgcn_mfma_f32_16x16x32_bf16

__device__ __forceinline__ unsigned short f2bfu(float f){
  unsigned int u = __float_as_uint(f);
  return (unsigned short)((u + 0x7fffu + ((u >> 16) & 1u)) >> 16);   // RNE
}
__device__ __forceinline__ float bfu2f(unsigned short u){
  return __uint_as_float(((unsigned int)u) << 16);
}
// manual RNE pack (proven R0-R3/R5; the v_cvt_pk_bf16_f32 asm variant broke R4)
__device__ __forceinline__ unsigned int pack2(float a, float b){
  return (unsigned int)f2bfu(a) | ((unsigned int)f2bfu(b) << 16);
}
// async 16B global->LDS (per-lane gptr; LDS dest = base + lane*16)
__device__ __forceinline__ void async16(const void* g, void* l){
  __builtin_amdgcn_global_load_lds(
    (const __attribute__((address_space(1))) unsigned int*)g,
    (__attribute__((address_space(3))) unsigned int*)l, 16, 0, 0);
}
// swizzle: permute 8-elem k-groups within each 64-elem block by row&7
__device__ __forceinline__ int swz(int col, int row){
  return (col & ~63) | (((((col>>3)&7) ^ (row&7)))<<3) | (col&7);
}

// ---------- LayerNorm row body: one wave per row (fp32 in, swizzled bf16 out) ----------
__device__ __forceinline__ void ln_row(const float* __restrict__ x,
    const float* __restrict__ g, const float* __restrict__ bb,
    bf16* __restrict__ y, long row, int lane){
  const float* xr = x + row * kH + lane*8;
  float4 a = *(const float4*)xr, c = *(const float4*)(xr+4);
  float v[8] = {a.x,a.y,a.z,a.w,c.x,c.y,c.z,c.w};
  float s=0.f, s2=0.f;
#pragma unroll
  for(int i=0;i<8;i++){ s += v[i]; s2 += v[i]*v[i]; }
#pragma unroll
  for(int o=32; o>=1; o>>=1){ s += __shfl_xor(s,o,64); s2 += __shfl_xor(s2,o,64); }
  float mu  = s * (1.f/kH);
  float rs  = rsqrtf(s2*(1.f/kH) - mu*mu + 1e-5f);
  float gv[8], bv[8];
  {
    float4 t0=*(const float4*)(g+lane*8),  t1=*(const float4*)(g+lane*8+4);
    float4 t2=*(const float4*)(bb+lane*8), t3=*(const float4*)(bb+lane*8+4);
    gv[0]=t0.x;gv[1]=t0.y;gv[2]=t0.z;gv[3]=t0.w;gv[4]=t1.x;gv[5]=t1.y;gv[6]=t1.z;gv[7]=t1.w;
    bv[0]=t2.x;bv[1]=t2.y;bv[2]=t2.z;bv[3]=t2.w;bv[4]=t3.x;bv[5]=t3.y;bv[6]=t3.z;bv[7]=t3.w;
  }
  unsigned int ow[4];
#pragma unroll
  for(int i=0;i<4;i++){
    float a0 = (v[2*i]  -mu)*rs*gv[2*i]   + bv[2*i];
    float a1 = (v[2*i+1]-mu)*rs*gv[2*i+1] + bv[2*i+1];
    ow[i] = pack2(a0, a1);
  }
  *reinterpret_cast<uint4*>(y + row*kH + swz(lane*8, (int)row)) = make_uint4(ow[0],ow[1],ow[2],ow[3]);
}

__global__ __launch_bounds__(256) void ln_kernel(const float* __restrict__ x,
    const float* __restrict__ g, const float* __restrict__ bb, bf16* __restrict__ y){
  ln_row(x, g, bb, y, (long)blockIdx.x*4 + (threadIdx.x>>6), threadIdx.x&63);
}

// ---------- weight prep tile body: W[K,N] fp32 -> WT[N,K] bf16, k-group swizzled ----------
__device__ __forceinline__ void prep_tile(const float* __restrict__ W,
    bf16* __restrict__ WT, int K, int N, int kb, int nb){
  __shared__ unsigned short Ts[64*68];
  int tid=threadIdx.x;
  {
    int k=tid>>2, nc=(tid&3)*16;
    const float* p = W + (size_t)(kb+k)*N + nb+nc;
#pragma unroll
    for(int i=0;i<16;i+=4){
      float4 f = *(const float4*)(p+i);
      Ts[k*68+nc+i  ]=f2bfu(f.x); Ts[k*68+nc+i+1]=f2bfu(f.y);
      Ts[k*68+nc+i+2]=f2bfu(f.z); Ts[k*68+nc+i+3]=f2bfu(f.w);
    }
  }
  __syncthreads();
  {
    int n=tid>>2, kc=(tid&3)*16;
    unsigned short tmp[16];
#pragma unroll
    for(int i=0;i<16;i++) tmp[i] = Ts[(kc+i)*68 + n];
    int row = nb+n, kg0 = kc>>3;
    bf16* op = WT + (size_t)row*K + kb;
    *(uint4*)(op + (((kg0  ^(row&7)))<<3)) = *(uint4*)&tmp[0];
    *(uint4*)(op + ((((kg0+1)^(row&7)))<<3)) = *(uint4*)&tmp[8];
  }
}

// ---------- merged: ln1 (blocks 0..2047) + Wq/Wk/Wv prep (blocks 2048..2239) ----------
__global__ __launch_bounds__(256) void ln1_prep_qkv(
    const float* __restrict__ x, const float* __restrict__ g, const float* __restrict__ bb,
    bf16* __restrict__ y, const float* __restrict__ Wq, const float* __restrict__ Wk,
    const float* __restrict__ Wv, bf16* __restrict__ WT){
  int id = blockIdx.x;
  if(id < 2048){
    ln_row(x, g, bb, y, (long)id*4 + (threadIdx.x>>6), threadIdx.x&63);
  } else {
    int pid = id - 2048, sel = pid>>6, lid = pid&63;
    const float* W = sel==0 ? Wq : (sel==1 ? Wk : Wv);
    prep_tile(W, WT + (size_t)sel*262144, kH, kH, (lid>>3)*64, (lid&7)*64);
  }
}

// ---------- merged prep of Wo (64) + W1 (256) + W2 (256) ----------
__global__ __launch_bounds__(256) void prep_rest(
    const float* __restrict__ Wo, const float* __restrict__ W1, const float* __restrict__ W2,
    bf16* __restrict__ WoT, bf16* __restrict__ W1T, bf16* __restrict__ W2T){
  int id = blockIdx.x;
  const float* W; bf16* WT; int K, N, kb, nb;
  if(id < 64)       { W=Wo; WT=WoT; K=kH;   N=kH;   kb=(id>>3)*64;        nb=(id&7)*64; }
  else if(id < 320) { int l=id-64;  W=W1; WT=W1T; K=kH;   N=kFFN; kb=(l>>5)*64; nb=(l&31)*64; }
  else              { int l=id-320; W=W2; WT=W2T; K=kFFN; N=kH;   kb=(l>>3)*64; nb=(l&7)*64; }
  prep_tile(W, WT, K, N, kb, nb);
}

// ---------- bias_eff: bf16 be[row,key] = mask ? bias : -1e9 ----------
__global__ __launch_bounds__(256) void bias_eff_kernel(
    const int* __restrict__ mask, const float* __restrict__ bias, bf16* __restrict__ be){
  size_t i8 = ((size_t)blockIdx.x*256 + threadIdx.x)*8;
  int4   m0 = *(const int4*)(mask+i8),   m1 = *(const int4*)(mask+i8+4);
  float4 b0 = *(const float4*)(bias+i8), b1 = *(const float4*)(bias+i8+4);
  const unsigned short NEG = f2bfu(-1e9f);
  unsigned short o[8];
  o[0]=m0.x?f2bfu(b0.x):NEG; o[1]=m0.y?f2bfu(b0.y):NEG;
  o[2]=m0.z?f2bfu(b0.z):NEG; o[3]=m0.w?f2bfu(b0.w):NEG;
  o[4]=m1.x?f2bfu(b1.x):NEG; o[5]=m1.y?f2bfu(b1.y):NEG;
  o[6]=m1.z?f2bfu(b1.z):NEG; o[7]=m1.w?f2bfu(b1.w):NEG;
  *(uint4*)((unsigned short*)be + i8) = *(uint4*)o;
}

// ---------- m97-style MFMA GEMM, generalized tile (BM x BN), 64x64 per wave ----------
template<int BM, int BN, typename OutT, bool SCALE, bool GELU, bool RES, bool CSW>
__global__ __launch_bounds__((BM/64)*(BN/64)*64, 3) void mfma_gemm(
    const bf16* __restrict__ A, const bf16* __restrict__ BT,
    const float* __restrict__ bias, const float* __restrict__ res,
    OutT* __restrict__ C, int M, int N, int K)
{
  constexpr int W  = (BM/64)*(BN/64);
  constexpr int NW = BN/64;
  constexpr int AC = (BM/8)/W, BC = (BN/8)/W;
  __shared__ __align__(16) unsigned short As[BM*64];
  __shared__ __align__(16) unsigned short Bs[BN*64];
  int tid=threadIdx.x, lane=tid&63, quad=lane>>4, l16=lane&15;
  int w=__builtin_amdgcn_readfirstlane(tid>>6);
  int wr = w / NW, wc = w % NW;
  int m0=blockIdx.y*BM, n0=blockIdx.x*BN;
  int lr=lane>>3, lc=lane&7;
  float4v acc[4][4] = {};
  for(int k0=0;k0<K;k0+=64){
    __syncthreads();
#pragma unroll
    for(int i=0;i<AC;i++){
      int r = (w*AC+i)*8;
      async16(A + (size_t)(m0+r+lr)*K + k0 + lc*8, &As[r*64]);
    }
#pragma unroll
    for(int i=0;i<BC;i++){
      int r = (w*BC+i)*8;
      async16(BT + (size_t)(n0+r+lr)*K + k0 + lc*8, &Bs[r*64]);
    }
    __syncthreads();
#pragma unroll
    for(int hf=0;hf<2;hf++){
      short8 af[4], bfv[4];
#pragma unroll
      for(int mi=0;mi<4;mi++){
        int row=wr*64+mi*16+l16;
        af[mi]=*(const short8*)&As[row*64 + (((hf*4+quad)^(row&7))<<3)];
      }
#pragma unroll
      for(int ni=0;ni<4;ni++){
        int n=wc*64+ni*16+l16;
        bfv[ni]=*(const short8*)&Bs[n*64 + (((hf*4+quad)^(n&7))<<3)];
      }
#pragma unroll
      for(int ni=0;ni<4;ni++)
#pragma unroll
        for(int mi=0;mi<4;mi++)
          acc[mi][ni]=MFMA16(af[mi],bfv[ni],acc[mi][ni],0,0,0);
    }
  }
#pragma unroll
  for(int ni=0;ni<4;ni++){
    int col=n0+wc*64+ni*16+l16;
    float bc=bias[col];
#pragma unroll
    for(int mi=0;mi<4;mi++){
#pragma unroll
      for(int r=0;r<4;r++){
        int row=m0+wr*64+mi*16+quad*4+r;
        float v=acc[mi][ni][r]+bc;
        if constexpr(SCALE) v*=0.125f;
        if constexpr(GELU)  v=0.5f*v*(1.f+erff(v*0.70710678118f));
        size_t idx=(size_t)row*N+col;
        if constexpr(RES) v+=res[idx];
        if constexpr(std::is_same<OutT,float>::value) C[idx]=v;
        else {
          size_t ix = CSW ? ((size_t)row*N + swz(col,row)) : idx;
          reinterpret_cast<unsigned short*>(C)[ix]=f2bfu(v);
        }
      }
    }
  }
}

// ---------- quad GEMM: 64x64 tile, 4 waves (32x32 quadrants), 2-phase double-buffered ----
// fp32 out + residual. Stage kt+1 before computing kt (pattern proven in attn R5);
// one barrier per iter. LDS 32 KB -> 4 blocks/CU.
__global__ __launch_bounds__(256, 4) void quad_gemm(
    const bf16* __restrict__ A, const bf16* __restrict__ BT,
    const float* __restrict__ bias, const float* __restrict__ res,
    float* __restrict__ C, int M, int N, int K)
{
  __shared__ __align__(16) unsigned short As[2][64*64];
  __shared__ __align__(16) unsigned short Bs[2][64*64];
  int tid=threadIdx.x, lane=tid&63, quad=lane>>4, l16=lane&15;
  int w=__builtin_amdgcn_readfirstlane(tid>>6);
  int wr=w>>1, wc=w&1;
  int m0=blockIdx.y*64, n0=blockIdx.x*64;
  int lr=lane>>3, lc=lane&7;
  float4v acc[2][2]={};
  auto stage=[&](int k0,int bi){
#pragma unroll
    for(int i=0;i<2;i++){
      int r=(w*2+i)*8;
      async16(A  + (size_t)(m0+r+lr)*K + k0 + lc*8, &As[bi][r*64]);
      async16(BT + (size_t)(n0+r+lr)*K + k0 + lc*8, &Bs[bi][r*64]);
    }
  };
  stage(0,0);
  __syncthreads();
  int NT = K>>6;
  for(int kt=0;kt<NT;kt++){
    int cur=kt&1;
    if(kt+1<NT) stage((kt+1)<<6, cur^1);   // next tile's loads in flight over compute
#pragma unroll
    for(int hf=0;hf<2;hf++){
      short8 af[2], bfv[2];
#pragma unroll
      for(int mi=0;mi<2;mi++){
        int row=wr*32+mi*16+l16;
        af[mi]=*(const short8*)&As[cur][row*64 + (((hf*4+quad)^(row&7))<<3)];
      }
#pragma unroll
      for(int ni=0;ni<2;ni++){
        int n=wc*32+ni*16+l16;
        bfv[ni]=*(const short8*)&Bs[cur][n*64 + (((hf*4+quad)^(n&7))<<3)];
      }
#pragma unroll
      for(int ni=0;ni<2;ni++)
#pragma unroll
        for(int mi=0;mi<2;mi++)
          acc[mi][ni]=MFMA16(af[mi],bfv[ni],acc[mi][ni],0,0,0);
    }
    __syncthreads();   // next buffer staged + all waves done reading [cur]
  }
#pragma unroll
  for(int ni=0;ni<2;ni++){
    int col=n0+wc*32+ni*16+l16;
    float bc=bias[col];
#pragma unroll
    for(int mi=0;mi<2;mi++){
#pragma unroll
      for(int r=0;r<4;r++){
        int row=m0+wr*32+mi*16+quad*4+r;
        float v=acc[mi][ni][r]+bc;
        size_t idx=(size_t)row*N+col;
        v+=res[idx];
        C[idx]=v;
      }
    }
  }
}

// ---------- fused QKV GEMM: 128x128 tile; BT = [Wq|Wk|Wv]^T rows 0..1535 ----------
__global__ __launch_bounds__(256, 3) void mfma_gemm_qkv(
    const bf16* __restrict__ A, const bf16* __restrict__ BT,
    const float* __restrict__ bq, const float* __restrict__ bk, const float* __restrict__ bv,
    bf16* __restrict__ qo, bf16* __restrict__ ko, bf16* __restrict__ vT, int M, int N, int K)
{
  __shared__ __align__(16) unsigned short As[128*64];
  __shared__ __align__(16) unsigned short Bs[128*64];
  int tid=threadIdx.x, lane=tid&63, quad=lane>>4, l16=lane&15;
  int w=__builtin_amdgcn_readfirstlane(tid>>6);
  int wr = w >> 1, wc = w & 1;
  int m0=blockIdx.y*128, n0=blockIdx.x*128;
  int lr=lane>>3, lc=lane&7;
  float4v acc[4][4] = {};
  for(int k0=0;k0<K;k0+=64){
    __syncthreads();
#pragma unroll
    for(int i=0;i<4;i++){
      int r = (w*4+i)*8;
      async16(A + (size_t)(m0+r+lr)*K + k0 + lc*8, &As[r*64]);
    }
#pragma unroll
    for(int i=0;i<4;i++){
      int r = (w*4+i)*8;
      async16(BT + (size_t)(n0+r+lr)*K + k0 + lc*8, &Bs[r*64]);
    }
    __syncthreads();
#pragma unroll
    for(int hf=0;hf<2;hf++){
      short8 af[4], bfv[4];
#pragma unroll
      for(int mi=0;mi<4;mi++){
        int row=wr*64+mi*16+l16;
        af[mi]=*(const short8*)&As[row*64 + (((hf*4+quad)^(row&7))<<3)];
      }
#pragma unroll
      for(int ni=0;ni<4;ni++){
        int n=wc*64+ni*16+l16;
        bfv[ni]=*(const short8*)&Bs[n*64 + (((hf*4+quad)^(n&7))<<3)];
      }
#pragma unroll
      for(int ni=0;ni<4;ni++)
#pragma unroll
        for(int mi=0;mi<4;mi++)
          acc[mi][ni]=MFMA16(af[mi],bfv[ni],acc[mi][ni],0,0,0);
    }
  }
  int sec = __builtin_amdgcn_readfirstlane(n0 >> 9);    // 0=q, 1=k, 2=v (block-uniform)
  const float* bp = sec==0 ? bq : (sec==1 ? bk : bv);
  if(sec == 2){
#pragma unroll
    for(int ni=0;ni<4;ni++){
      int cl=(n0+wc*64+ni*16+l16)&511;
      float bc=bp[cl];
#pragma unroll
      for(int mi=0;mi<4;mi++){
        int row0=m0+wr*64+mi*16+quad*4;
        unsigned int p0=pack2(acc[mi][ni][0]+bc, acc[mi][ni][1]+bc);
        unsigned int p1=pack2(acc[mi][ni][2]+bc, acc[mi][ni][3]+bc);
        *reinterpret_cast<uint2*>(reinterpret_cast<unsigned short*>(vT)
            + (size_t)cl*8192 + row0) = make_uint2(p0,p1);
      }
    }
  } else {
    unsigned short* dst = (unsigned short*)(sec==0 ? qo : ko);
    float scl = (sec==0) ? 0.125f : 1.0f;
#pragma unroll
    for(int ni=0;ni<4;ni++){
      int col=n0+wc*64+ni*16+l16, cl=col&511;
      float bc=bp[cl];
#pragma unroll
      for(int mi=0;mi<4;mi++){
#pragma unroll
        for(int r=0;r<4;r++){
          int row=m0+wr*64+mi*16+quad*4+r;
          dst[(size_t)row*512+cl]=f2bfu((acc[mi][ni][r]+bc)*scl);
        }
      }
    }
  }
}

// ---------- MFMA flash attention (fixed-max softmax, 2-phase, 128 q-rows/block) ----------
// Grid 512 = 8 q-tiles x 64 bh, XCD-swizzled (each XCD owns one batch b).
// 4 waves; wave w owns q-rows w*32..+31 as two 16-row groups g=0,1 (independent chains).
// be bf16 [8192][1024] gathered to regs (prefetched one tile ahead); O -> swizzled bf16.
__global__ __launch_bounds__(256,2) void attn_mfma(
    const bf16* __restrict__ q, const bf16* __restrict__ k,
    const bf16* __restrict__ vT, const bf16* __restrict__ be,
    bf16* __restrict__ o)
{
  __shared__ __align__(16) unsigned short Ks[2][64*64];   // [key][d] xor-swizzled
  __shared__ __align__(16) unsigned short Vt[2][64*64];   // [d][key] xor-swizzled
  __shared__ __align__(16) unsigned short Ps[4*32*72];    // per-wave P (32 rows), stride 72
  int tid=threadIdx.x, lane=tid&63, quad=lane>>4, l16=lane&15;
  int w=__builtin_amdgcn_readfirstlane(tid>>6);
  // XCD swizzle: 512 blocks = 8 XCDs x 64; XCD x gets bh 8x..8x+7 (= batch x, all heads)
  int lin = blockIdx.x;
  int nid = (lin&7)*64 + (lin>>3);
  int q0=(nid&7)*128, bh=nid>>3, b=bh>>3, h=bh&7;
  int lr=lane>>3, lc=lane&7;
  short8 aq[2][2];
#pragma unroll
  for(int g=0;g<2;g++){
    const bf16* qp = q + (size_t)(b*kS + q0 + w*32 + g*16 + l16)*kH + h*64;
    aq[g][0] = *(const short8*)(qp + quad*8);
    aq[g][1] = *(const short8*)(qp + 32 + quad*8);
  }
  float lpart[2][4]={};
  float4v oacc[2][4]={};
  int pb = w*32*72;
  const unsigned short* beRow[2][4];
#pragma unroll
  for(int g=0;g<2;g++)
#pragma unroll
    for(int r=0;r<4;r++)
      beRow[g][r] = reinterpret_cast<const unsigned short*>(be)
                  + (size_t)(b*kS+q0+w*32+g*16+quad*4+r)*kS + l16;

  auto stage = [&](int kt, int bufi){
    int kb = kt*64;
#pragma unroll
    for(int i=0;i<2;i++){
      int rr = w*16 + i*8;
      async16(k  + (size_t)(b*kS+kb+rr+lr)*kH + h*64 + ((lc^lr)<<3), &Ks[bufi][rr*64]);
      async16(vT + (size_t)(h*64+rr+lr)*8192 + b*kS + kb + ((lc^lr)<<3), &Vt[bufi][rr*64]);
    }
  };
  float bevc[2][4][4];   // [g][r][t] C-init for current tile (prefetched)
  stage(0,0);
#pragma unroll
  for(int g=0;g<2;g++)
#pragma unroll
    for(int r=0;r<4;r++)
#pragma unroll
      for(int t=0;t<4;t++)
        bevc[g][r][t] = bfu2f(beRow[g][r][t*16]);
  __syncthreads();
  for(int kt=0;kt<16;kt++){
    int cur=kt&1;
    if(kt<15) stage(kt+1, cur^1);          // next tile's K/V loads in flight over compute
    // S = Q·K^T + bias (two independent 16-row chains)
    float4v sa[2][4];
    __builtin_amdgcn_s_setprio(1);
#pragma unroll
    for(int t=0;t<4;t++){
      int krow=t*16+l16, kx=krow&7;
      short8 b0 = *(const short8*)&Ks[cur][krow*64 + ((quad^kx)<<3)];
      short8 b1 = *(const short8*)&Ks[cur][krow*64 + (((4+quad)^kx)<<3)];
#pragma unroll
      for(int g=0;g<2;g++){
        float4v ci;
#pragma unroll
        for(int r=0;r<4;r++) ci[r] = bevc[g][r][t];
        ci = MFMA16(aq[g][0],b0,ci,0,0,0);
        sa[g][t]=MFMA16(aq[g][1],b1,ci,0,0,0);
      }
    }
    __builtin_amdgcn_s_setprio(0);
    // prefetch next tile's bias C-init (bevc dead after QK; latency hides under SM+PV)
    if(kt<15){
      int kb2=(kt+1)*64;
#pragma unroll
      for(int g=0;g<2;g++)
#pragma unroll
        for(int r=0;r<4;r++)
#pragma unroll
          for(int t=0;t<4;t++)
            bevc[g][r][t] = bfu2f(beRow[g][r][kb2 + t*16]);
    }
    // fixed-max softmax: P = exp(s - 24); defer cross-lane l-reduction
#pragma unroll
    for(int g=0;g<2;g++)
#pragma unroll
    for(int t=0;t<4;t++){
      int kg = t*2 + (l16>>3), j = l16&7;
#pragma unroll
      for(int r=0;r<4;r++){
        float p = __expf(sa[g][t][r] - 24.f);
        lpart[g][r] += p;
        int row = g*16 + quad*4+r;
        Ps[pb + row*72 + ((kg^(row&7))<<3) + j] = f2bfu(p);
      }
    }
    short8 ap[2][2];
#pragma unroll
    for(int g=0;g<2;g++){
      int prow = g*16 + l16;
      ap[g][0] = *(const short8*)&Ps[pb + prow*72 + ((quad^(prow&7))<<3)];
      ap[g][1] = *(const short8*)&Ps[pb + prow*72 + (((4+quad)^(prow&7))<<3)];
    }
    __builtin_amdgcn_s_setprio(1);
#pragma unroll
    for(int dt=0;dt<4;dt++){
      int vrow=dt*16+l16, vx=vrow&7;
      short8 bv0=*(const short8*)&Vt[cur][vrow*64+((quad^vx)<<3)];
      short8 bv1=*(const short8*)&Vt[cur][vrow*64+(((4+quad)^vx)<<3)];
#pragma unroll
      for(int g=0;g<2;g++){
        oacc[g][dt]=MFMA16(ap[g][0],bv0,oacc[g][dt],0,0,0);
        oacc[g][dt]=MFMA16(ap[g][1],bv1,oacc[g][dt],0,0,0);
      }
    }
    __builtin_amdgcn_s_setprio(0);
    __syncthreads();   // next buffer staged + all waves done reading [cur]
  }
#pragma unroll
  for(int g=0;g<2;g++){
    float inv[4];
#pragma unroll
    for(int r=0;r<4;r++){
      float l = lpart[g][r];
      l += __shfl_xor(l,1,64); l += __shfl_xor(l,2,64);
      l += __shfl_xor(l,4,64); l += __shfl_xor(l,8,64);
      inv[r] = 1.f/l;
    }
#pragma unroll
    for(int dt=0;dt<4;dt++)
#pragma unroll
      for(int r=0;r<4;r++){
        int row = b*kS + q0 + w*32 + g*16 + quad*4 + r;
        int col = h*64 + dt*16 + l16;
        reinterpret_cast<unsigned short*>(o)[(size_t)row*kH + swz(col,row)] =
          f2bfu(oacc[g][dt][r]*inv[r]);
      }
  }
}

// ---------- launch ----------
extern "C" void kernel_launch(void* const* d_in, const int* in_sizes, int n_in,
                              void* d_out, int out_size, void* d_ws, size_t ws_size,
                              hipStream_t stream){
  (void)in_sizes; (void)n_in; (void)out_size; (void)ws_size;
  const float* x         = (const float*)d_in[0];
  const float* attn_bias = (const float*)d_in[1];
  const int*   graph_mask= (const int*)  d_in[2];
  const float* ln1_g = (const float*)d_in[3];
  const float* ln1_b = (const float*)d_in[4];
  const float* Wq = (const float*)d_in[5];
  const float* bq = (const float*)d_in[6];
  const float* Wk = (const float*)d_in[7];
  const float* bk = (const float*)d_in[8];
  const float* Wv = (const float*)d_in[9];
  const float* bv = (const float*)d_in[10];
  const float* Wo = (const float*)d_in[11];
  const float* bo = (const float*)d_in[12];
  const float* ln2_g = (const float*)d_in[13];
  const float* ln2_b = (const float*)d_in[14];
  const float* W1 = (const float*)d_in[15];
  const float* b1 = (const float*)d_in[16];
  const float* W2 = (const float*)d_in[17];
  const float* b2 = (const float*)d_in[18];

  // ws (32 MiB): s0 y1->O->y2 | s1 q->h | s2 k->h | s3 vT->WoT/W1T/W2T
  char* wsb = (char*)d_ws;
  const size_t SZ = (size_t)8192 * kH * sizeof(bf16);   // 8 MiB
  bf16* s0 = (bf16*)(wsb);
  bf16* s1 = (bf16*)(wsb + SZ);
  bf16* s2 = (bf16*)(wsb + 2*SZ);
  bf16* s3 = (bf16*)(wsb + 3*SZ);
  float* outf = (float*)d_out;        // WqkvT -> bias_eff(beP) -> residual/output
  bf16*  WqkvT = (bf16*)d_out;                              // 1.5 MiB: [Wq|Wk|Wv]^T
  bf16*  beP   = (bf16*)d_out;                              // 16 MiB (after QKV GEMM)
  bf16* WoT = s3;
  bf16* W1T = s3 + 262144;
  bf16* W2T = s3 + 262144 + 1048576;

  dim3 blk(256);
  // 1: LN1 + Wq/Wk/Wv transpose (independent work, one dispatch)
  ln1_prep_qkv<<<dim3(2240), blk, 0, stream>>>(x, ln1_g, ln1_b, s0, Wq, Wk, Wv, WqkvT);
  // 2: fused QKV: q->s1 (scaled), k->s2, v->s3 transposed (vT)
  mfma_gemm_qkv<<<dim3(12,64), blk, 0, stream>>>(s0, WqkvT, bq, bk, bv, s1, s2, s3, 8192, 3*kH, kH);
  // 3: bias_eff (overwrites WqkvT region of d_out; QKV done with it)
  bias_eff_kernel<<<dim3(4096), blk, 0, stream>>>(graph_mask, attn_bias, beP);
  // 4: attention (512 blocks, 128 q-rows each)
  attn_mfma<<<dim3(512), blk, 0, stream>>>(s1, s2, s3, beP, s0);
  // 5: Wo/W1/W2 transpose into s3 (vT dead after attn)
  prep_rest<<<dim3(576), blk, 0, stream>>>(Wo, W1, W2, WoT, W1T, W2T);
  // 6: O-proj + residual (quad: 64x64 dbuf, 4-wave, 4 blocks/CU)
  quad_gemm<<<dim3(8,128), blk, 0, stream>>>(s0, WoT, bo, x, outf, 8192, kH, kH);
  // 7: LN2
  ln_kernel<<<dim3(2048), blk, 0, stream>>>(outf, ln2_g, ln2_b, s0);
  // 8-11: FFN, 2 chunks of 4096 rows; h (16 MiB) spans s1+s2
  for(int c=0;c<2;c++){
    size_t ro = (size_t)c * 4096 * kH;
    mfma_gemm<128,128,bf16,false,true ,false,true ><<<dim3(16,32), blk, 0, stream>>>(s0 + ro, W1T, b1, nullptr, s1, 4096, kFFN, kH);
    quad_gemm<<<dim3(8,64), blk, 0, stream>>>(s1, W2T, b2, outf + ro, outf + ro, 4096, kH, kFFN);
  }
}